// Round 16
// baseline (2018.915 us; speedup 1.0000x reference)
//
#include <hip/hip_runtime.h>

#define NS_ 26
#define NCLS_ 97

typedef short bf16x8 __attribute__((ext_vector_type(8)));
typedef float f32x4 __attribute__((ext_vector_type(4)));

__device__ __forceinline__ unsigned short f2bf(float f) {
  union { float f; unsigned u; } v; v.f = f;
  unsigned r = v.u + 0x7fffu + ((v.u >> 16) & 1u);
  return (unsigned short)(r >> 16);
}
__device__ __forceinline__ float bf2f(unsigned short h) {
  union { unsigned u; float f; } v; v.u = ((unsigned)h) << 16;
  return v.f;
}
__device__ __forceinline__ float sigm_f(float x) { return 1.f / (1.f + __expf(-x)); }
__device__ __forceinline__ float tanh_f(float x) { return 1.f - 2.f / (1.f + __expf(2.f * x)); }

__device__ __forceinline__ void gl_lds16(const void* g, void* l) {
  __builtin_amdgcn_global_load_lds(
      (const __attribute__((address_space(1))) unsigned int*)g,
      (__attribute__((address_space(3))) unsigned int*)l, 16, 0, 0);
}

// ---- LLC-coherent 16B ops (bypass L1+L2; device-visible after vmcnt drain) ----
__device__ __forceinline__ bf16x8 llcld(const unsigned short* p) {
  bf16x8 v;
  asm volatile("global_load_dwordx4 %0, %1, off sc0 sc1\ns_waitcnt vmcnt(0)"
               : "=v"(v) : "v"(p) : "memory");
  return v;
}
__device__ __forceinline__ void llcst(unsigned short* p, bf16x8 v) {
  asm volatile("global_store_dwordx4 %0, %1, off sc0 sc1" :: "v"(p), "v"(v) : "memory");
}

// light group barrier (32 blocks): no cache fences; data goes via sc0sc1 ops.
__device__ __forceinline__ void gbar(unsigned* bar, unsigned* gen, unsigned target) {
  asm volatile("s_waitcnt vmcnt(0)" ::: "memory");
  __syncthreads();
  if (threadIdx.x == 0) {
    const unsigned prev = __hip_atomic_fetch_add(bar, 1u, __ATOMIC_RELAXED, __HIP_MEMORY_SCOPE_AGENT);
    if (prev + 1u == target * 32u) {
      __hip_atomic_store(gen, target, __ATOMIC_RELAXED, __HIP_MEMORY_SCOPE_AGENT);
    } else {
      while (__hip_atomic_load(gen, __ATOMIC_RELAXED, __HIP_MEMORY_SCOPE_AGENT) < target) {}
    }
  }
  __syncthreads();
}

// ============ tiled 128x128 GEMM (prologue) ============
template <bool OUTF>
__global__ __launch_bounds__(256) void gemm_tiled_k(
    const unsigned short* __restrict__ Ag, const unsigned short* __restrict__ Bg,
    const float* __restrict__ bias, float* __restrict__ outF,
    unsigned short* __restrict__ outB, int K, long ldo, int Nvalid) {
  __shared__ unsigned short As[128 * 64];
  __shared__ unsigned short Bs[128 * 64];
  const int tid = threadIdx.x;
  const int w = tid >> 6, l = tid & 63;
  const int l15 = l & 15, lq = l >> 4;
  const int wm = w >> 1, wn = w & 1;
  const long rowBase = (long)blockIdx.y * 128;
  const long colBase = (long)blockIdx.x * 128;
  const int lrow = l >> 3, ps_st = l & 7;
  f32x4 acc[4][4] = {};
  for (int kt = 0; kt < K; kt += 64) {
#pragma unroll
    for (int i = 0; i < 4; ++i) {
      const int row = i * 32 + w * 8 + lrow;
      const int ls = ps_st ^ (row & 7);
      gl_lds16(Ag + (rowBase + row) * K + kt + ls * 8, As + i * 2048 + w * 512);
      gl_lds16(Bg + (colBase + row) * K + kt + ls * 8, Bs + i * 2048 + w * 512);
    }
    __syncthreads();
#pragma unroll
    for (int kh = 0; kh < 2; ++kh) {
      bf16x8 af[4], bfr[4];
#pragma unroll
      for (int mi = 0; mi < 4; ++mi) {
        const int row = wm * 64 + mi * 16 + l15;
        const int ps = (kh * 4 + lq) ^ (row & 7);
        af[mi] = *(const bf16x8*)(As + row * 64 + ps * 8);
      }
#pragma unroll
      for (int ni = 0; ni < 4; ++ni) {
        const int row = wn * 64 + ni * 16 + l15;
        const int ps = (kh * 4 + lq) ^ (row & 7);
        bfr[ni] = *(const bf16x8*)(Bs + row * 64 + ps * 8);
      }
#pragma unroll
      for (int mi = 0; mi < 4; ++mi)
#pragma unroll
        for (int ni = 0; ni < 4; ++ni)
          acc[mi][ni] = __builtin_amdgcn_mfma_f32_16x16x32_bf16(af[mi], bfr[ni], acc[mi][ni], 0, 0, 0);
    }
    __syncthreads();
  }
#pragma unroll
  for (int mi = 0; mi < 4; ++mi)
#pragma unroll
    for (int ni = 0; ni < 4; ++ni) {
      const long gcol = colBase + wn * 64 + ni * 16 + l15;
      if (gcol >= Nvalid) continue;
      const float bv = bias ? bias[gcol] : 0.f;
#pragma unroll
      for (int r = 0; r < 4; ++r) {
        const long grow = rowBase + wm * 64 + mi * 16 + lq * 4 + r;
        const float v = acc[mi][ni][r] + bv;
        if (OUTF) outF[grow * ldo + gcol] = v;
        else      outB[grow * ldo + gcol] = f2bf(v);
      }
    }
}

// ============ persistent scan: 256 blocks x 1024 thr; 8 groups x 32 blocks ============
struct CoopArgs {
  const unsigned short* Hproj;   // [B,64,512] bf16 (normal)
  const unsigned short* bH;      // [B,64,512] bf16 (normal)
  const unsigned short* Wt4;     // [128][512][4] packed W_h2h (normal)
  const unsigned short* Wfz;     // [1024,512] bf16 (normal)
  const unsigned short* FZpre;   // [B*NS,1024] bf16 (normal)
  const unsigned short* Wihh;    // [2048,1280] bf16 (normal)
  const unsigned short* embb;    // [B,NS,256] bf16 (normal)
  const float* b_h2h;            // [512]
  const float* w_score;          // [512]
  const float* bf1;              // [512]
  const float* biasG;            // [2048]
  float* out_attn;               // [B,64,NS] (normal)
  float* out_char;               // [B,NS,512] (normal)
  float* out_hid;                // [B,NS,512] (normal)
  float* cbuf;                   // [B,512] f32 (block-private, normal)
  unsigned short* ctx;           // [B,512] bf16 (LLC)
  unsigned short* Ichar;         // [B,512] bf16 (LLC)
  unsigned short* hbuf;          // 2x [B,512] bf16 (LLC)
  unsigned* bars;                // 8 groups x 32 uints
};

__global__ __launch_bounds__(1024, 4) void scan_coop_k(CoopArgs A) {
  __shared__ float ws_t[520];
  __shared__ __align__(16) char smraw[52224];
  const int tid = threadIdx.x;
  const int bx = blockIdx.x;
  const int g = bx & 7, lb = bx >> 3;
  const long rb = (long)g * 64;
  unsigned* bar = A.bars + g * 32;
  unsigned* gen = bar + 1;
  unsigned tgt = 0;

  if (tid < 512) ws_t[(tid & 7) * 65 + (tid >> 3)] = A.w_score[tid];
  __syncthreads();

  for (int s = 0; s < NS_; ++s) {
    const unsigned short* hrd = A.hbuf + (s & 1) * 262144;
    unsigned short* hwr = A.hbuf + ((s + 1) & 1) * 262144;

    // ======== P1: hp GEMV + attention (2 rows per block) ========
    {
      const long b0 = rb + lb * 2;
      float* hs     = (float*)smraw;               // [2][512]  (4096 B)
      float* gpart  = (float*)(smraw + 4096);      // [2 halves][2 rows][512] (8192 B)
      float* hp_t   = (float*)(smraw + 12288);     // [2][520]  (4160 B)
      float* e_s    = (float*)(smraw + 16448);     // [2][64]   (512 B)
      float* cpart  = (float*)(smraw + 16960);     // [2][8][520] (33280 B) -> ends 50240
      float* colsum = (float*)(smraw + 4096);      // reuse gpart region after GEMV
      // load h rows (f32 in LDS)
      if (tid < 128) {
        const int row = tid >> 6, c = tid & 63;
        const bf16x8 v = llcld(hrd + (b0 + row) * 512 + c * 8);
#pragma unroll
        for (int j = 0; j < 8; ++j) hs[row * 512 + c * 8 + j] = bf2f((unsigned short)v[j]);
      }
      __syncthreads();
      // GEMV: thread (half=tid>>9, j=tid&511) partial over k in [half*256,(half+1)*256)
      {
        const int half = tid >> 9, j = tid & 511;
        const unsigned short* wp = A.Wt4 + (long)half * 64 * 2048 + j * 4;
        const float* h0 = hs;
        const float* h1 = hs + 512;
        float a0 = 0.f, a1 = 0.f;
#pragma unroll 8
        for (int k4 = 0; k4 < 64; ++k4) {
          const ushort4 wv = *(const ushort4*)(wp + k4 * 2048);
          const int kb = (half * 64 + k4) * 4;
          const float w0 = bf2f(wv.x), w1 = bf2f(wv.y), w2 = bf2f(wv.z), w3 = bf2f(wv.w);
          a0 += w0 * h0[kb] + w1 * h0[kb + 1] + w2 * h0[kb + 2] + w3 * h0[kb + 3];
          a1 += w0 * h1[kb] + w1 * h1[kb + 1] + w2 * h1[kb + 2] + w3 * h1[kb + 3];
        }
        gpart[half * 1024 + j] = a0;
        gpart[half * 1024 + 512 + j] = a1;
      }
      __syncthreads();
      {
        const int pair = tid >> 9, j = tid & 511;
        const float hpv = gpart[pair * 512 + j] + gpart[1024 + pair * 512 + j] + A.b_h2h[j];
        hp_t[pair * 520 + (j & 7) * 65 + (j >> 3)] = hpv;
      }
      __syncthreads();
      // score: 16 waves; wave w: row = w>>3, t-chunk (w&7)*8..+8
      const int w16 = tid >> 6, l = tid & 63;
      const int srow = w16 >> 3;
      const float* hpT = hp_t + srow * 520;
#pragma unroll
      for (int tt = 0; tt < 8; ++tt) {
        const int t = (w16 & 7) * 8 + tt;
        const bf16x8 hv = *(const bf16x8*)(A.Hproj + ((b0 + srow) * 64 + t) * 512 + l * 8);
        float acc = 0.f;
#pragma unroll
        for (int j = 0; j < 8; ++j)
          acc += tanh_f(bf2f((unsigned short)hv[j]) + hpT[j * 65 + l]) * ws_t[j * 65 + l];
        acc += __shfl_xor(acc, 1);
        acc += __shfl_xor(acc, 2);
        acc += __shfl_xor(acc, 4);
        acc += __shfl_xor(acc, 8);
        acc += __shfl_xor(acc, 16);
        acc += __shfl_xor(acc, 32);
        if (l == 0) e_s[srow * 64 + t] = acc;
      }
      __syncthreads();
      if ((w16 & 7) == 0) {
        const float e = e_s[srow * 64 + l];
        float m = e;
        for (int off = 32; off; off >>= 1) m = fmaxf(m, __shfl_xor(m, off));
        const float p = __expf(e - m);
        float sum = p;
        for (int off = 32; off; off >>= 1) sum += __shfl_xor(sum, off);
        const float a = p / sum;
        e_s[srow * 64 + l] = a;
        A.out_attn[((b0 + srow) * 64 + l) * NS_ + s] = a;
      }
      __syncthreads();
      // context: 8 t-groups x 64 col-chunks per row-team; 16-B loads
      {
        const int ssb = tid >> 9;
        const int sstid = tid & 511;
        const long b = b0 + ssb;
        const int tg = sstid >> 6;
        const int c8 = sstid & 63;
        const float* al = e_s + ssb * 64 + tg * 8;
        const unsigned short* bhp = A.bH + (b * 64 + tg * 8) * 512 + c8 * 8;
        float a8[8] = {};
#pragma unroll
        for (int tt = 0; tt < 8; ++tt) {
          const bf16x8 v = *(const bf16x8*)(bhp + (long)tt * 512);
          const float a = al[tt];
#pragma unroll
          for (int j = 0; j < 8; ++j) a8[j] += a * bf2f((unsigned short)v[j]);
        }
        float* pp = cpart + ssb * 4160 + tg * 520 + c8 * 8;
#pragma unroll
        for (int j = 0; j < 8; ++j) pp[j] = a8[j];
      }
      __syncthreads();
      {
        const int ssb = tid >> 9;
        const int j = tid & 511;
        const float* pp = cpart + ssb * 4160 + j;
        const float sum = pp[0] + pp[520] + pp[1040] + pp[1560]
                        + pp[2080] + pp[2600] + pp[3120] + pp[3640];
        colsum[ssb * 512 + j] = sum;
      }
      __syncthreads();
      {
        const int ssb = tid >> 9;
        const int sstid = tid & 511;
        if (sstid < 64) {
          const float* cs = colsum + ssb * 512 + sstid * 8;
          bf16x8 v;
#pragma unroll
          for (int j = 0; j < 8; ++j) v[j] = (short)f2bf(cs[j]);
          llcst(A.ctx + (b0 + ssb) * 512 + sstid * 8, v);
        }
      }
    }
    gbar(bar, gen, ++tgt);

    // ======== P2: gated fusion (32 units: 4 bt x 8 jt of 16r x 64c) ========
    {
      const int j0 = (lb & 7) * 64;
      const long b0 = rb + (lb >> 3) * 16;
      unsigned short* ctxs = (unsigned short*)smraw;           // [16][520]
      float* ls = (float*)(smraw + 16640);                     // [2][16][65]
      unsigned short* ist = (unsigned short*)(smraw + 24960);  // [16][64]
      {
        const int row = tid >> 6, c = tid & 63;
        const bf16x8 v = llcld(A.ctx + (b0 + row) * 512 + c * 8);
        *(bf16x8*)(ctxs + row * 520 + c * 8) = v;
      }
      __syncthreads();
      if (tid < 512) {
        const int w = tid >> 6, l = tid & 63, l15 = l & 15, lq = l >> 4;
        const int which = w >> 2, nh = w & 3;
        f32x4 acc = {};
        const long gw = (long)(which ? 512 : 0) + j0 + nh * 16 + l15;
#pragma unroll
        for (int kt = 0; kt < 512; kt += 64) {
          const int k0 = kt + lq * 8, k1 = k0 + 32;
          const bf16x8 a0 = *(const bf16x8*)(ctxs + l15 * 520 + k0);
          const bf16x8 a1 = *(const bf16x8*)(ctxs + l15 * 520 + k1);
          const bf16x8 w0 = *(const bf16x8*)(A.Wfz + gw * 512 + k0);
          const bf16x8 w1 = *(const bf16x8*)(A.Wfz + gw * 512 + k1);
          acc = __builtin_amdgcn_mfma_f32_16x16x32_bf16(a0, w0, acc, 0, 0, 0);
          acc = __builtin_amdgcn_mfma_f32_16x16x32_bf16(a1, w1, acc, 0, 0, 0);
        }
#pragma unroll
        for (int r = 0; r < 4; ++r)
          ls[which * 1040 + (lq * 4 + r) * 65 + nh * 16 + l15] = acc[r];
      }
      __syncthreads();
      {
        const int r = tid >> 6, c = tid & 63;
        const long b = b0 + r;
        const int j = j0 + c;
        const float f1 = tanh_f(ls[r * 65 + c] + A.bf1[j]);
        const float zc = ls[1040 + r * 65 + c];
        const long pr = (b * NS_ + s) * 1024;
        const float f2 = tanh_f(bf2f(A.FZpre[pr + j]));
        const float z = sigm_f(zc + bf2f(A.FZpre[pr + 512 + j]));
        const float I = z * f1 + (1.f - z) * f2;
        A.out_char[(b * NS_ + s) * 512 + j] = I;
        ist[r * 64 + c] = f2bf(I);
      }
      __syncthreads();
      if (tid < 128) {
        const int row = tid >> 3, c = tid & 7;
        const bf16x8 v = *(const bf16x8*)(ist + row * 64 + c * 8);
        llcst(A.Ichar + (b0 + row) * 512 + j0 + c * 8, v);
      }
    }
    gbar(bar, gen, ++tgt);

    // ======== P3: gates + LSTM (32 blocks: 4 bt x 8 jp; 2 sub-units of 16r x 32c) ========
    {
      const int bt = lb & 3, jp = lb >> 2;
      const long b0 = rb + bt * 16;
      unsigned short* ichs = (unsigned short*)smraw;           // [16][520]
      unsigned short* hss = (unsigned short*)(smraw + 16640);  // [16][520]
      float* gs = (float*)(smraw + 33280);                     // [2][4][16][33]
      unsigned short* hst = (unsigned short*)(smraw + 50176);  // [2][16][32]
      for (int t = tid; t < 2048; t += 1024) {
        const int arr = t >> 10, q = t & 1023;
        const int row = q >> 6, c = q & 63;
        if (arr == 0) {
          const bf16x8 v = llcld(A.Ichar + (b0 + row) * 512 + c * 8);
          *(bf16x8*)(ichs + row * 520 + c * 8) = v;
        } else {
          const bf16x8 v = llcld(hrd + (b0 + row) * 512 + c * 8);
          *(bf16x8*)(hss + row * 520 + c * 8) = v;
        }
      }
      __syncthreads();
      {
        const int sb = tid >> 9, st = tid & 511;
        const int w = st >> 6, l = st & 63, l15 = l & 15, lq = l >> 4;
        const int g4 = w & 3, ni = w >> 2;
        const int j0 = jp * 64 + sb * 32;
        const unsigned short* wptr = A.Wihh + ((long)g4 * 512 + j0 + ni * 16 + l15) * 1280;
        const unsigned short* eptr = A.embb + ((b0 + l15) * NS_ + s) * 256;
        f32x4 acc = {};
#pragma unroll
        for (int kt = 0; kt < 1280; kt += 64) {
          const int k0 = kt + lq * 8, k1 = k0 + 32;
          bf16x8 a0, a1;
          a0 = (k0 < 512) ? *(const bf16x8*)(ichs + l15 * 520 + k0)
             : (k0 < 768) ? *(const bf16x8*)(eptr + (k0 - 512))
                          : *(const bf16x8*)(hss + l15 * 520 + (k0 - 768));
          a1 = (k1 < 512) ? *(const bf16x8*)(ichs + l15 * 520 + k1)
             : (k1 < 768) ? *(const bf16x8*)(eptr + (k1 - 512))
                          : *(const bf16x8*)(hss + l15 * 520 + (k1 - 768));
          const bf16x8 w0 = *(const bf16x8*)(wptr + k0);
          const bf16x8 w1 = *(const bf16x8*)(wptr + k1);
          acc = __builtin_amdgcn_mfma_f32_16x16x32_bf16(a0, w0, acc, 0, 0, 0);
          acc = __builtin_amdgcn_mfma_f32_16x16x32_bf16(a1, w1, acc, 0, 0, 0);
        }
        float* gss = gs + sb * 2112;
#pragma unroll
        for (int r = 0; r < 4; ++r)
          gss[(g4 * 16 + lq * 4 + r) * 33 + ni * 16 + l15] = acc[r];
      }
      __syncthreads();
      {
        const int sb = tid >> 9, e = tid & 511;
        const int r = e >> 5, c = e & 31;
        const long b = b0 + r;
        const int j = jp * 64 + sb * 32 + c;
        const float* gss = gs + sb * 2112;
        const float ig = sigm_f(gss[(0 * 16 + r) * 33 + c] + A.biasG[j]);
        const float fg = sigm_f(gss[(1 * 16 + r) * 33 + c] + A.biasG[512 + j]);
        const float gg = tanh_f(gss[(2 * 16 + r) * 33 + c] + A.biasG[1024 + j]);
        const float og = sigm_f(gss[(3 * 16 + r) * 33 + c] + A.biasG[1536 + j]);
        const float cn = fg * A.cbuf[b * 512 + j] + ig * gg;
        A.cbuf[b * 512 + j] = cn;
        const float h = og * tanh_f(cn);
        A.out_hid[(b * NS_ + s) * 512 + j] = h;
        hst[sb * 512 + r * 32 + c] = f2bf(h);
      }
      __syncthreads();
      if (tid < 128) {
        const int sb = tid >> 6, q = tid & 63;
        const int row = q >> 2, c = q & 3;
        const bf16x8 v = *(const bf16x8*)(hst + sb * 512 + row * 32 + c * 8);
        llcst(hwr + (b0 + row) * 512 + jp * 64 + sb * 32 + c * 8, v);
      }
    }
    gbar(bar, gen, ++tgt);
  }
}

// ============ final probs GEMM ============
__global__ __launch_bounds__(256) void probs_k(
    const float* __restrict__ Af, const unsigned short* __restrict__ Wg,
    const float* __restrict__ bias, float* __restrict__ outp) {
  const int tid = threadIdx.x, w = tid >> 6, l = tid & 63, l15 = l & 15, lq = l >> 4;
  const long mrow = (long)blockIdx.y * 64 + w * 16 + l15;
  const int nbase = blockIdx.x * 64;
  f32x4 acc[4] = {};
  for (int kt = 0; kt < 512; kt += 32) {
    const int k = kt + lq * 8;
    const float4 av0 = *(const float4*)(Af + mrow * 512 + k);
    const float4 av1 = *(const float4*)(Af + mrow * 512 + k + 4);
    bf16x8 a;
    a[0] = (short)f2bf(av0.x); a[1] = (short)f2bf(av0.y);
    a[2] = (short)f2bf(av0.z); a[3] = (short)f2bf(av0.w);
    a[4] = (short)f2bf(av1.x); a[5] = (short)f2bf(av1.y);
    a[6] = (short)f2bf(av1.z); a[7] = (short)f2bf(av1.w);
#pragma unroll
    for (int nb = 0; nb < 4; ++nb) {
      const bf16x8 b = *(const bf16x8*)(Wg + (long)(nbase + nb * 16 + l15) * 512 + k);
      acc[nb] = __builtin_amdgcn_mfma_f32_16x16x32_bf16(a, b, acc[nb], 0, 0, 0);
    }
  }
#pragma unroll
  for (int nb = 0; nb < 4; ++nb) {
    const int colg = nbase + nb * 16 + l15;
    if (colg >= NCLS_) continue;
    const float bv = bias[colg];
#pragma unroll
    for (int r = 0; r < 4; ++r) {
      const long rowg = (long)blockIdx.y * 64 + w * 16 + lq * 4 + r;
      outp[rowg * NCLS_ + colg] = acc[nb][r] + bv;
    }
  }
}

// ============ mega-cvt: batch_H | AS | W_i2h -> bf16 ============
#define CVT_N0 4194304L
#define CVT_N1 1703936L
#define CVT_N2 65536L
__global__ void mega_cvt_k(const float* __restrict__ batch_H, const float* __restrict__ AS,
                           const float* __restrict__ W_i2h,
                           unsigned short* __restrict__ bH, unsigned short* __restrict__ ASb,
                           unsigned short* __restrict__ Wi2hb) {
  const long q = (long)blockIdx.x * 256 + threadIdx.x;
  const float* src; unsigned short* dst; long i;
  if (q < CVT_N0) { src = batch_H; dst = bH; i = q; }
  else if (q < CVT_N0 + CVT_N1) { src = AS; dst = ASb; i = q - CVT_N0; }
  else if (q < CVT_N0 + CVT_N1 + CVT_N2) { src = W_i2h; dst = Wi2hb; i = q - CVT_N0 - CVT_N1; }
  else return;
  const float4 v = *(const float4*)(src + i * 4);
  ushort4 o;
  o.x = f2bf(v.x); o.y = f2bf(v.y); o.z = f2bf(v.z); o.w = f2bf(v.w);
  *(ushort4*)(dst + i * 4) = o;
}

// ============ mega-pack ============
#define PK_N0 2621440L   // Wihh
#define PK_N1 524288L    // Wfz
#define PK_N2 524288L    // Wfz2
#define PK_N3 65536L     // Wgen
#define PK_N4 262144L    // Wt4 (packed W_h2h)
#define PK_N5 3072L      // biases
#define PK_N6 3407872L   // embed
__global__ void mega_pack_k(
    const float* __restrict__ W_ih, const float* __restrict__ W_hh,
    const float* __restrict__ Wf1, const float* __restrict__ Wf2,
    const float* __restrict__ Wz, const float* __restrict__ W_gen,
    const float* __restrict__ W_h2h,
    const float* __restrict__ b_ih, const float* __restrict__ b_hh,
    const float* __restrict__ bf2, const float* __restrict__ bz,
    const float* __restrict__ emb_table, const int* __restrict__ text,
    unsigned short* __restrict__ Wihh, unsigned short* __restrict__ Wfz,
    unsigned short* __restrict__ Wfz2, unsigned short* __restrict__ Wgenb,
    unsigned short* __restrict__ Wt4, float* __restrict__ biasG,
    float* __restrict__ biasFZ, unsigned short* __restrict__ embb) {
  long q = (long)blockIdx.x * 256 + threadIdx.x;
  if (q < PK_N0) {
    const int row = (int)(q / 1280), c = (int)(q % 1280);
    const float v = (c < 768) ? W_ih[(long)row * 768 + c] : W_hh[(long)row * 512 + (c - 768)];
    Wihh[q] = f2bf(v);
    return;
  }
  q -= PK_N0;
  if (q < PK_N1) {
    const int row = (int)(q >> 9), k = (int)(q & 511);
    const float v = (row < 512) ? Wf1[(long)row * 512 + k] : Wz[(long)(row - 512) * 1024 + k];
    Wfz[q] = f2bf(v);
    return;
  }
  q -= PK_N1;
  if (q < PK_N2) {
    const int row = (int)(q >> 9), k = (int)(q & 511);
    const float v = (row < 512) ? Wf2[(long)row * 512 + k]
                                : Wz[(long)(row - 512) * 1024 + 512 + k];
    Wfz2[q] = f2bf(v);
    return;
  }
  q -= PK_N2;
  if (q < PK_N3) {
    const int row = (int)(q >> 9), k = (int)(q & 511);
    Wgenb[q] = (row < NCLS_) ? f2bf(W_gen[(long)row * 512 + k]) : (unsigned short)0;
    return;
  }
  q -= PK_N3;
  if (q < PK_N4) {
    // Wt4[(k>>2)*2048 + j*4 + (k&3)] = W_h2h[j][k]
    const int j = (int)(q >> 9), k = (int)(q & 511);
    Wt4[((long)(k >> 2) * 2048) + j * 4 + (k & 3)] = f2bf(W_h2h[q]);
    return;
  }
  q -= PK_N4;
  if (q < PK_N5) {
    if (q < 2048) biasG[q] = b_ih[q] + b_hh[q];
    else {
      const int j = (int)(q - 2048);
      biasFZ[j] = (j < 512) ? bf2[j] : bz[j - 512];
    }
    return;
  }
  q -= PK_N5;
  if (q < PK_N6) {
    const long bs = q >> 8;
    const int j = (int)(q & 255);
    const int t = text[bs];
    embb[q] = f2bf(emb_table[(long)t * 256 + j]);
  }
}

extern "C" void kernel_launch(void* const* d_in, const int* in_sizes, int n_in,
                              void* d_out, int out_size, void* d_ws, size_t ws_size,
                              hipStream_t stream) {
  (void)in_sizes; (void)n_in; (void)out_size; (void)ws_size;
  const float* batch_H  = (const float*)d_in[0];
  const float* AS       = (const float*)d_in[1];
  const int*   text     = (const int*)d_in[2];
  const float* W_i2h    = (const float*)d_in[3];
  const float* W_h2h    = (const float*)d_in[4];
  const float* b_h2h    = (const float*)d_in[5];
  const float* w_score  = (const float*)d_in[6];
  const float* W_ih     = (const float*)d_in[7];
  const float* W_hh     = (const float*)d_in[8];
  const float* b_ih     = (const float*)d_in[9];
  const float* b_hh     = (const float*)d_in[10];
  const float* Wf1      = (const float*)d_in[11];
  const float* bf1      = (const float*)d_in[12];
  const float* Wf2      = (const float*)d_in[13];
  const float* bf2      = (const float*)d_in[14];
  const float* Wz       = (const float*)d_in[15];
  const float* bz       = (const float*)d_in[16];
  const float* W_gen    = (const float*)d_in[17];
  const float* b_gen    = (const float*)d_in[18];
  const float* emb_tab  = (const float*)d_in[19];

  float* out = (float*)d_out;
  float* out_probs = out;
  float* out_attn  = out + 1291264;
  float* out_hid   = out + 2143232;
  float* out_char  = out + 8958976;

  char* wsp = (char*)d_ws;
  auto alloc = [&](size_t bytes) { char* p = wsp; wsp += (bytes + 255) & ~(size_t)255; return p; };
  unsigned short* bH    = (unsigned short*)alloc(33554432);
  unsigned short* Hproj = (unsigned short*)alloc(33554432);
  unsigned short* ASb   = (unsigned short*)alloc(13631488);
  unsigned short* embb  = (unsigned short*)alloc(6815744);
  unsigned short* FZpre = (unsigned short*)alloc(27262976);
  unsigned short* Wt4   = (unsigned short*)alloc(524288);
  unsigned short* Wfz   = (unsigned short*)alloc(1048576);
  unsigned short* Wfz2  = (unsigned short*)alloc(1048576);
  unsigned short* Wihh  = (unsigned short*)alloc(5242880);
  unsigned short* Wgenb = (unsigned short*)alloc(131072);
  unsigned short* Wi2hb = (unsigned short*)alloc(524288);
  float* biasG          = (float*)alloc(8192);
  float* biasFZ         = (float*)alloc(4096);
  unsigned* bars        = (unsigned*)alloc(1024);
  char* ab = (char*)ASb;
  unsigned short* ctx   = (unsigned short*)(ab);
  unsigned short* Ichar = (unsigned short*)(ab + 524288);
  float* cbuf           = (float*)(ab + 1048576);
  unsigned short* hbuf  = (unsigned short*)(ab + 2097152);

  // -------- prologue --------
  mega_cvt_k<<<dim3(23297), dim3(256), 0, stream>>>(batch_H, AS, W_i2h, bH, ASb, Wi2hb);
  mega_pack_k<<<dim3(28960), dim3(256), 0, stream>>>(
      W_ih, W_hh, Wf1, Wf2, Wz, W_gen, W_h2h, b_ih, b_hh, bf2, bz, emb_tab, text,
      Wihh, Wfz, Wfz2, Wgenb, Wt4, biasG, biasFZ, embb);

  gemm_tiled_k<false><<<dim3(4, 256), dim3(256), 0, stream>>>(
      bH, Wi2hb, nullptr, nullptr, Hproj, 512, 512, 512);

  gemm_tiled_k<false><<<dim3(8, 104), dim3(256), 0, stream>>>(
      ASb, Wfz2, biasFZ, nullptr, FZpre, 512, 1024, 1024);

  hipMemsetAsync(cbuf, 0, 1048576, stream);
  hipMemsetAsync(hbuf, 0, 1048576, stream);
  hipMemsetAsync(bars, 0, 1024, stream);

  // -------- persistent 26-step scan (256 blocks x 1024 thr; 3 barriers/step) --------
  CoopArgs ca;
  ca.Hproj = Hproj; ca.bH = bH; ca.Wt4 = Wt4; ca.Wfz = Wfz; ca.FZpre = FZpre;
  ca.Wihh = Wihh; ca.embb = embb;
  ca.b_h2h = b_h2h; ca.w_score = w_score; ca.bf1 = bf1; ca.biasG = biasG;
  ca.out_attn = out_attn; ca.out_char = out_char; ca.out_hid = out_hid;
  ca.cbuf = cbuf; ca.ctx = ctx; ca.Ichar = Ichar; ca.hbuf = hbuf; ca.bars = bars;
  void* kargs[] = { (void*)&ca };
  hipLaunchCooperativeKernel((const void*)scan_coop_k, dim3(256), dim3(1024), kargs, 0, stream);

  // probs = out_hid @ W_gen^T + b_gen
  probs_k<<<dim3(2, 208), dim3(256), 0, stream>>>(out_hid, Wgenb, b_gen, out_probs);
}

// Round 17
// 1640.699 us; speedup vs baseline: 1.2305x; 1.2305x over previous
//
#include <hip/hip_runtime.h>

#define NS_ 26
#define NCLS_ 97

typedef short bf16x8 __attribute__((ext_vector_type(8)));
typedef float f32x4 __attribute__((ext_vector_type(4)));

__device__ __forceinline__ unsigned short f2bf(float f) {
  union { float f; unsigned u; } v; v.f = f;
  unsigned r = v.u + 0x7fffu + ((v.u >> 16) & 1u);
  return (unsigned short)(r >> 16);
}
__device__ __forceinline__ float bf2f(unsigned short h) {
  union { unsigned u; float f; } v; v.u = ((unsigned)h) << 16;
  return v.f;
}
__device__ __forceinline__ float sigm_f(float x) { return 1.f / (1.f + __expf(-x)); }
__device__ __forceinline__ float tanh_f(float x) { return 1.f - 2.f / (1.f + __expf(2.f * x)); }

__device__ __forceinline__ void gl_lds16(const void* g, void* l) {
  __builtin_amdgcn_global_load_lds(
      (const __attribute__((address_space(1))) unsigned int*)g,
      (__attribute__((address_space(3))) unsigned int*)l, 16, 0, 0);
}

// ---- LLC-coherent 16B ops (bypass L1+L2; device-visible after vmcnt drain) ----
__device__ __forceinline__ bf16x8 llcld(const unsigned short* p) {
  bf16x8 v;
  asm volatile("global_load_dwordx4 %0, %1, off sc0 sc1\ns_waitcnt vmcnt(0)"
               : "=v"(v) : "v"(p) : "memory");
  return v;
}
__device__ __forceinline__ void llcst(unsigned short* p, bf16x8 v) {
  asm volatile("global_store_dwordx4 %0, %1, off sc0 sc1" :: "v"(p), "v"(v) : "memory");
}
__device__ __forceinline__ f32x4 llcldf(const float* p) {
  f32x4 v;
  asm volatile("global_load_dwordx4 %0, %1, off sc0 sc1\ns_waitcnt vmcnt(0)"
               : "=v"(v) : "v"(p) : "memory");
  return v;
}
__device__ __forceinline__ void llcstf(float* p, f32x4 v) {
  asm volatile("global_store_dwordx4 %0, %1, off sc0 sc1" :: "v"(p), "v"(v) : "memory");
}

// light group barrier (32 blocks): no cache fences; data goes via sc0sc1 ops.
__device__ __forceinline__ void gbar(unsigned* bar, unsigned* gen, unsigned target) {
  asm volatile("s_waitcnt vmcnt(0)" ::: "memory");
  __syncthreads();
  if (threadIdx.x == 0) {
    const unsigned prev = __hip_atomic_fetch_add(bar, 1u, __ATOMIC_RELAXED, __HIP_MEMORY_SCOPE_AGENT);
    if (prev + 1u == target * 32u) {
      __hip_atomic_store(gen, target, __ATOMIC_RELAXED, __HIP_MEMORY_SCOPE_AGENT);
    } else {
      while (__hip_atomic_load(gen, __ATOMIC_RELAXED, __HIP_MEMORY_SCOPE_AGENT) < target) {}
    }
  }
  __syncthreads();
}

// ============ tiled 128x128 GEMM (prologue) ============
template <bool OUTF>
__global__ __launch_bounds__(256) void gemm_tiled_k(
    const unsigned short* __restrict__ Ag, const unsigned short* __restrict__ Bg,
    const float* __restrict__ bias, float* __restrict__ outF,
    unsigned short* __restrict__ outB, int K, long ldo, int Nvalid) {
  __shared__ unsigned short As[128 * 64];
  __shared__ unsigned short Bs[128 * 64];
  const int tid = threadIdx.x;
  const int w = tid >> 6, l = tid & 63;
  const int l15 = l & 15, lq = l >> 4;
  const int wm = w >> 1, wn = w & 1;
  const long rowBase = (long)blockIdx.y * 128;
  const long colBase = (long)blockIdx.x * 128;
  const int lrow = l >> 3, ps_st = l & 7;
  f32x4 acc[4][4] = {};
  for (int kt = 0; kt < K; kt += 64) {
#pragma unroll
    for (int i = 0; i < 4; ++i) {
      const int row = i * 32 + w * 8 + lrow;
      const int ls = ps_st ^ (row & 7);
      gl_lds16(Ag + (rowBase + row) * K + kt + ls * 8, As + i * 2048 + w * 512);
      gl_lds16(Bg + (colBase + row) * K + kt + ls * 8, Bs + i * 2048 + w * 512);
    }
    __syncthreads();
#pragma unroll
    for (int kh = 0; kh < 2; ++kh) {
      bf16x8 af[4], bfr[4];
#pragma unroll
      for (int mi = 0; mi < 4; ++mi) {
        const int row = wm * 64 + mi * 16 + l15;
        const int ps = (kh * 4 + lq) ^ (row & 7);
        af[mi] = *(const bf16x8*)(As + row * 64 + ps * 8);
      }
#pragma unroll
      for (int ni = 0; ni < 4; ++ni) {
        const int row = wn * 64 + ni * 16 + l15;
        const int ps = (kh * 4 + lq) ^ (row & 7);
        bfr[ni] = *(const bf16x8*)(Bs + row * 64 + ps * 8);
      }
#pragma unroll
      for (int mi = 0; mi < 4; ++mi)
#pragma unroll
        for (int ni = 0; ni < 4; ++ni)
          acc[mi][ni] = __builtin_amdgcn_mfma_f32_16x16x32_bf16(af[mi], bfr[ni], acc[mi][ni], 0, 0, 0);
    }
    __syncthreads();
  }
#pragma unroll
  for (int mi = 0; mi < 4; ++mi)
#pragma unroll
    for (int ni = 0; ni < 4; ++ni) {
      const long gcol = colBase + wn * 64 + ni * 16 + l15;
      if (gcol >= Nvalid) continue;
      const float bv = bias ? bias[gcol] : 0.f;
#pragma unroll
      for (int r = 0; r < 4; ++r) {
        const long grow = rowBase + wm * 64 + mi * 16 + lq * 4 + r;
        const float v = acc[mi][ni][r] + bv;
        if (OUTF) outF[grow * ldo + gcol] = v;
        else      outB[grow * ldo + gcol] = f2bf(v);
      }
    }
}

// ============ persistent scan: 256 blocks x 1024 thr; 8 groups x 32 blocks ============
struct CoopArgs {
  const unsigned short* Hproj;   // [B,64,512] bf16 (normal)
  const unsigned short* bH;      // [B,64,512] bf16 (normal)
  const unsigned short* Wh2hb;   // [512,512] bf16 (normal)
  const unsigned short* Wfz;     // [1024,512] bf16 (normal)
  const unsigned short* FZpre;   // [B*NS,1024] bf16 (normal)
  const unsigned short* Wihh;    // [2048,1280] bf16 (normal)
  const unsigned short* embb;    // [B,NS,256] bf16 (normal)
  const float* b_h2h;            // [512]
  const float* w_score;          // [512]
  const float* bf1;              // [512]
  const float* biasG;            // [2048]
  float* hp;                     // [512,512] f32 (LLC)
  float* out_attn;               // [B,64,NS] (normal)
  float* out_char;               // [B,NS,512] (normal)
  float* out_hid;                // [B,NS,512] (normal)
  float* cbuf;                   // [B,512] f32 (block-private, normal)
  unsigned short* ctx;           // [B,512] bf16 (LLC)
  unsigned short* Ichar;         // [B,512] bf16 (LLC)
  unsigned short* hbuf;          // 2x [B,512] bf16 (LLC)
  unsigned* bars;                // 8 groups x 32 uints
};

__global__ __launch_bounds__(1024, 4) void scan_coop_k(CoopArgs A) {
  __shared__ float ws_t[520];
  __shared__ __align__(16) char smraw[52224];
  const int tid = threadIdx.x;
  const int bx = blockIdx.x;
  const int g = bx & 7, lb = bx >> 3;
  const long rb = (long)g * 64;
  unsigned* bar = A.bars + g * 32;
  unsigned* gen = bar + 1;
  unsigned tgt = 0;

  if (tid < 512) ws_t[(tid & 7) * 65 + (tid >> 3)] = A.w_score[tid];
  __syncthreads();

  for (int s = 0; s < NS_; ++s) {
    const unsigned short* hrd = A.hbuf + (s & 1) * 262144;
    unsigned short* hwr = A.hbuf + ((s + 1) & 1) * 262144;

    // ======== P0: hp = h @ W_h2h^T + b_h2h (32 units: 4 bt x 8 jt of 16r x 64c) ========
    {
      const int bt = lb >> 3, jt = lb & 7;
      const long b0 = rb + bt * 16;
      const int j0 = jt * 64;
      unsigned short* h16 = (unsigned short*)smraw;   // [16][520]
      float* ls = (float*)(smraw + 16640);            // [2][16][65]
      float* hpo = (float*)(smraw + 24960);           // [16][64]
      {
        const int row = tid >> 6, c = tid & 63;
        const bf16x8 v = llcld(hrd + (b0 + row) * 512 + c * 8);
        *(bf16x8*)(h16 + row * 520 + c * 8) = v;
      }
      __syncthreads();
      if (tid < 512) {
        const int w = tid >> 6, l = tid & 63, l15 = l & 15, lq = l >> 4;
        const int kh = w >> 2, ni = w & 3;
        const unsigned short* wrow = A.Wh2hb + (long)(j0 + ni * 16 + l15) * 512 + kh * 256;
        const unsigned short* arow = h16 + l15 * 520 + kh * 256;
        f32x4 acc = {};
#pragma unroll
        for (int kt = 0; kt < 256; kt += 64) {
          const int k0 = kt + lq * 8, k1 = k0 + 32;
          const bf16x8 a0 = *(const bf16x8*)(arow + k0);
          const bf16x8 a1 = *(const bf16x8*)(arow + k1);
          const bf16x8 w0 = *(const bf16x8*)(wrow + k0);
          const bf16x8 w1 = *(const bf16x8*)(wrow + k1);
          acc = __builtin_amdgcn_mfma_f32_16x16x32_bf16(a0, w0, acc, 0, 0, 0);
          acc = __builtin_amdgcn_mfma_f32_16x16x32_bf16(a1, w1, acc, 0, 0, 0);
        }
#pragma unroll
        for (int r = 0; r < 4; ++r)
          ls[kh * 1040 + (lq * 4 + r) * 65 + ni * 16 + l15] = acc[r];
      }
      __syncthreads();
      {
        const int r = tid >> 6, c = tid & 63;
        hpo[r * 64 + c] = ls[r * 65 + c] + ls[1040 + r * 65 + c] + A.b_h2h[j0 + c];
      }
      __syncthreads();
      if (tid < 256) {
        const int row = tid >> 4, c = tid & 15;
        const f32x4 v = *(const f32x4*)(hpo + row * 64 + c * 4);
        llcstf(A.hp + (b0 + row) * 512 + j0 + c * 4, v);
      }
    }
    gbar(bar, gen, ++tgt);

    // ======== P1: attention (2 rows per block) ========
    {
      const long b0 = rb + lb * 2;
      float* hp_t = (float*)smraw;                // [2][520]
      float* e_s  = (float*)(smraw + 4160);       // [2][64]
      float* part = (float*)(smraw + 4672);       // [2][8][520]
      float* colsum = (float*)(smraw + 37952);    // [2][512]
      if (tid < 256) {
        const int row = tid >> 7, q = tid & 127;
        const f32x4 v = llcldf(A.hp + (b0 + row) * 512 + q * 4);
#pragma unroll
        for (int i = 0; i < 4; ++i) {
          const int j = q * 4 + i;
          hp_t[row * 520 + (j & 7) * 65 + (j >> 3)] = v[i];
        }
      }
      __syncthreads();
      const int w16 = tid >> 6, l = tid & 63;
      const int srow = w16 >> 3;
      const float* hpT = hp_t + srow * 520;
#pragma unroll
      for (int tt = 0; tt < 8; ++tt) {
        const int t = (w16 & 7) * 8 + tt;
        const bf16x8 hv = *(const bf16x8*)(A.Hproj + ((b0 + srow) * 64 + t) * 512 + l * 8);
        float acc = 0.f;
#pragma unroll
        for (int j = 0; j < 8; ++j)
          acc += tanh_f(bf2f((unsigned short)hv[j]) + hpT[j * 65 + l]) * ws_t[j * 65 + l];
        acc += __shfl_xor(acc, 1);
        acc += __shfl_xor(acc, 2);
        acc += __shfl_xor(acc, 4);
        acc += __shfl_xor(acc, 8);
        acc += __shfl_xor(acc, 16);
        acc += __shfl_xor(acc, 32);
        if (l == 0) e_s[srow * 64 + t] = acc;
      }
      __syncthreads();
      if ((w16 & 7) == 0) {
        const float e = e_s[srow * 64 + l];
        float m = e;
        for (int off = 32; off; off >>= 1) m = fmaxf(m, __shfl_xor(m, off));
        const float p = __expf(e - m);
        float sum = p;
        for (int off = 32; off; off >>= 1) sum += __shfl_xor(sum, off);
        const float a = p / sum;
        e_s[srow * 64 + l] = a;
        A.out_attn[((b0 + srow) * 64 + l) * NS_ + s] = a;
      }
      __syncthreads();
      // context: 8 t-groups x 64 col-chunks per row-team; 16-B loads, 8-deep MLP
      {
        const int ssb = tid >> 9;          // row-team 0/1
        const int sstid = tid & 511;
        const long b = b0 + ssb;
        const int tg = sstid >> 6;         // t-group 0..7
        const int c8 = sstid & 63;         // 8-col chunk
        const float* al = e_s + ssb * 64 + tg * 8;
        const unsigned short* bhp = A.bH + (b * 64 + tg * 8) * 512 + c8 * 8;
        float a8[8] = {};
#pragma unroll
        for (int tt = 0; tt < 8; ++tt) {
          const bf16x8 v = *(const bf16x8*)(bhp + (long)tt * 512);
          const float a = al[tt];
#pragma unroll
          for (int j = 0; j < 8; ++j) a8[j] += a * bf2f((unsigned short)v[j]);
        }
        float* pp = part + ssb * 4160 + tg * 520 + c8 * 8;
#pragma unroll
        for (int j = 0; j < 8; ++j) pp[j] = a8[j];
      }
      __syncthreads();
      {
        const int ssb = tid >> 9;
        const int j = tid & 511;
        const float* pp = part + ssb * 4160 + j;
        const float sum = pp[0] + pp[520] + pp[1040] + pp[1560]
                        + pp[2080] + pp[2600] + pp[3120] + pp[3640];
        colsum[ssb * 512 + j] = sum;
      }
      __syncthreads();
      {
        const int ssb = tid >> 9;
        const int sstid = tid & 511;
        if (sstid < 64) {
          const float* cs = colsum + ssb * 512 + sstid * 8;
          bf16x8 v;
#pragma unroll
          for (int j = 0; j < 8; ++j) v[j] = (short)f2bf(cs[j]);
          llcst(A.ctx + (b0 + ssb) * 512 + sstid * 8, v);
        }
      }
    }
    gbar(bar, gen, ++tgt);

    // ======== P2: gated fusion (32 units: 4 bt x 8 jt of 16r x 64c) ========
    {
      const int j0 = (lb & 7) * 64;
      const long b0 = rb + (lb >> 3) * 16;
      unsigned short* ctxs = (unsigned short*)smraw;           // [16][520]
      float* ls = (float*)(smraw + 16640);                     // [2][16][65]
      unsigned short* ist = (unsigned short*)(smraw + 24960);  // [16][64]
      {
        const int row = tid >> 6, c = tid & 63;
        const bf16x8 v = llcld(A.ctx + (b0 + row) * 512 + c * 8);
        *(bf16x8*)(ctxs + row * 520 + c * 8) = v;
      }
      __syncthreads();
      if (tid < 512) {
        const int w = tid >> 6, l = tid & 63, l15 = l & 15, lq = l >> 4;
        const int which = w >> 2, nh = w & 3;
        f32x4 acc = {};
        const long gw = (long)(which ? 512 : 0) + j0 + nh * 16 + l15;
#pragma unroll
        for (int kt = 0; kt < 512; kt += 64) {
          const int k0 = kt + lq * 8, k1 = k0 + 32;
          const bf16x8 a0 = *(const bf16x8*)(ctxs + l15 * 520 + k0);
          const bf16x8 a1 = *(const bf16x8*)(ctxs + l15 * 520 + k1);
          const bf16x8 w0 = *(const bf16x8*)(A.Wfz + gw * 512 + k0);
          const bf16x8 w1 = *(const bf16x8*)(A.Wfz + gw * 512 + k1);
          acc = __builtin_amdgcn_mfma_f32_16x16x32_bf16(a0, w0, acc, 0, 0, 0);
          acc = __builtin_amdgcn_mfma_f32_16x16x32_bf16(a1, w1, acc, 0, 0, 0);
        }
#pragma unroll
        for (int r = 0; r < 4; ++r)
          ls[which * 1040 + (lq * 4 + r) * 65 + nh * 16 + l15] = acc[r];
      }
      __syncthreads();
      {
        const int r = tid >> 6, c = tid & 63;
        const long b = b0 + r;
        const int j = j0 + c;
        const float f1 = tanh_f(ls[r * 65 + c] + A.bf1[j]);
        const float zc = ls[1040 + r * 65 + c];
        const long pr = (b * NS_ + s) * 1024;
        const float f2 = tanh_f(bf2f(A.FZpre[pr + j]));
        const float z = sigm_f(zc + bf2f(A.FZpre[pr + 512 + j]));
        const float I = z * f1 + (1.f - z) * f2;
        A.out_char[(b * NS_ + s) * 512 + j] = I;
        ist[r * 64 + c] = f2bf(I);
      }
      __syncthreads();
      if (tid < 128) {
        const int row = tid >> 3, c = tid & 7;
        const bf16x8 v = *(const bf16x8*)(ist + row * 64 + c * 8);
        llcst(A.Ichar + (b0 + row) * 512 + j0 + c * 8, v);
      }
    }
    gbar(bar, gen, ++tgt);

    // ======== P3: gates + LSTM (32 blocks: 4 bt x 8 jp; 2 sub-units of 16r x 32c) ========
    {
      const int bt = lb & 3, jp = lb >> 2;
      const long b0 = rb + bt * 16;
      unsigned short* ichs = (unsigned short*)smraw;           // [16][520]
      unsigned short* hss = (unsigned short*)(smraw + 16640);  // [16][520]
      float* gs = (float*)(smraw + 33280);                     // [2][4][16][33]
      unsigned short* hst = (unsigned short*)(smraw + 50176);  // [2][16][32]
      for (int t = tid; t < 2048; t += 1024) {
        const int arr = t >> 10, q = t & 1023;
        const int row = q >> 6, c = q & 63;
        if (arr == 0) {
          const bf16x8 v = llcld(A.Ichar + (b0 + row) * 512 + c * 8);
          *(bf16x8*)(ichs + row * 520 + c * 8) = v;
        } else {
          const bf16x8 v = llcld(hrd + (b0 + row) * 512 + c * 8);
          *(bf16x8*)(hss + row * 520 + c * 8) = v;
        }
      }
      __syncthreads();
      {
        const int sb = tid >> 9, st = tid & 511;
        const int w = st >> 6, l = st & 63, l15 = l & 15, lq = l >> 4;
        const int g4 = w & 3, ni = w >> 2;
        const int j0 = jp * 64 + sb * 32;
        const unsigned short* wptr = A.Wihh + ((long)g4 * 512 + j0 + ni * 16 + l15) * 1280;
        const unsigned short* eptr = A.embb + ((b0 + l15) * NS_ + s) * 256;
        f32x4 acc = {};
#pragma unroll
        for (int kt = 0; kt < 1280; kt += 64) {
          const int k0 = kt + lq * 8, k1 = k0 + 32;
          bf16x8 a0, a1;
          a0 = (k0 < 512) ? *(const bf16x8*)(ichs + l15 * 520 + k0)
             : (k0 < 768) ? *(const bf16x8*)(eptr + (k0 - 512))
                          : *(const bf16x8*)(hss + l15 * 520 + (k0 - 768));
          a1 = (k1 < 512) ? *(const bf16x8*)(ichs + l15 * 520 + k1)
             : (k1 < 768) ? *(const bf16x8*)(eptr + (k1 - 512))
                          : *(const bf16x8*)(hss + l15 * 520 + (k1 - 768));
          const bf16x8 w0 = *(const bf16x8*)(wptr + k0);
          const bf16x8 w1 = *(const bf16x8*)(wptr + k1);
          acc = __builtin_amdgcn_mfma_f32_16x16x32_bf16(a0, w0, acc, 0, 0, 0);
          acc = __builtin_amdgcn_mfma_f32_16x16x32_bf16(a1, w1, acc, 0, 0, 0);
        }
        float* gss = gs + sb * 2112;
#pragma unroll
        for (int r = 0; r < 4; ++r)
          gss[(g4 * 16 + lq * 4 + r) * 33 + ni * 16 + l15] = acc[r];
      }
      __syncthreads();
      {
        const int sb = tid >> 9, e = tid & 511;
        const int r = e >> 5, c = e & 31;
        const long b = b0 + r;
        const int j = jp * 64 + sb * 32 + c;
        const float* gss = gs + sb * 2112;
        const float ig = sigm_f(gss[(0 * 16 + r) * 33 + c] + A.biasG[j]);
        const float fg = sigm_f(gss[(1 * 16 + r) * 33 + c] + A.biasG[512 + j]);
        const float gg = tanh_f(gss[(2 * 16 + r) * 33 + c] + A.biasG[1024 + j]);
        const float og = sigm_f(gss[(3 * 16 + r) * 33 + c] + A.biasG[1536 + j]);
        const float cn = fg * A.cbuf[b * 512 + j] + ig * gg;
        A.cbuf[b * 512 + j] = cn;
        const float h = og * tanh_f(cn);
        A.out_hid[(b * NS_ + s) * 512 + j] = h;
        hst[sb * 512 + r * 32 + c] = f2bf(h);
      }
      __syncthreads();
      if (tid < 128) {
        const int sb = tid >> 6, q = tid & 63;
        const int row = q >> 2, c = q & 3;
        const bf16x8 v = *(const bf16x8*)(hst + sb * 512 + row * 32 + c * 8);
        llcst(hwr + (b0 + row) * 512 + jp * 64 + sb * 32 + c * 8, v);
      }
    }
    gbar(bar, gen, ++tgt);
  }
}

// ============ final probs GEMM ============
__global__ __launch_bounds__(256) void probs_k(
    const float* __restrict__ Af, const unsigned short* __restrict__ Wg,
    const float* __restrict__ bias, float* __restrict__ outp) {
  const int tid = threadIdx.x, w = tid >> 6, l = tid & 63, l15 = l & 15, lq = l >> 4;
  const long mrow = (long)blockIdx.y * 64 + w * 16 + l15;
  const int nbase = blockIdx.x * 64;
  f32x4 acc[4] = {};
  for (int kt = 0; kt < 512; kt += 32) {
    const int k = kt + lq * 8;
    const float4 av0 = *(const float4*)(Af + mrow * 512 + k);
    const float4 av1 = *(const float4*)(Af + mrow * 512 + k + 4);
    bf16x8 a;
    a[0] = (short)f2bf(av0.x); a[1] = (short)f2bf(av0.y);
    a[2] = (short)f2bf(av0.z); a[3] = (short)f2bf(av0.w);
    a[4] = (short)f2bf(av1.x); a[5] = (short)f2bf(av1.y);
    a[6] = (short)f2bf(av1.z); a[7] = (short)f2bf(av1.w);
#pragma unroll
    for (int nb = 0; nb < 4; ++nb) {
      const bf16x8 b = *(const bf16x8*)(Wg + (long)(nbase + nb * 16 + l15) * 512 + k);
      acc[nb] = __builtin_amdgcn_mfma_f32_16x16x32_bf16(a, b, acc[nb], 0, 0, 0);
    }
  }
#pragma unroll
  for (int nb = 0; nb < 4; ++nb) {
    const int colg = nbase + nb * 16 + l15;
    if (colg >= NCLS_) continue;
    const float bv = bias[colg];
#pragma unroll
    for (int r = 0; r < 4; ++r) {
      const long rowg = (long)blockIdx.y * 64 + w * 16 + lq * 4 + r;
      outp[rowg * NCLS_ + colg] = acc[nb][r] + bv;
    }
  }
}

// ============ mega-cvt: batch_H | AS | W_i2h -> bf16 ============
#define CVT_N0 4194304L
#define CVT_N1 1703936L
#define CVT_N2 65536L
__global__ void mega_cvt_k(const float* __restrict__ batch_H, const float* __restrict__ AS,
                           const float* __restrict__ W_i2h,
                           unsigned short* __restrict__ bH, unsigned short* __restrict__ ASb,
                           unsigned short* __restrict__ Wi2hb) {
  const long q = (long)blockIdx.x * 256 + threadIdx.x;
  const float* src; unsigned short* dst; long i;
  if (q < CVT_N0) { src = batch_H; dst = bH; i = q; }
  else if (q < CVT_N0 + CVT_N1) { src = AS; dst = ASb; i = q - CVT_N0; }
  else if (q < CVT_N0 + CVT_N1 + CVT_N2) { src = W_i2h; dst = Wi2hb; i = q - CVT_N0 - CVT_N1; }
  else return;
  const float4 v = *(const float4*)(src + i * 4);
  ushort4 o;
  o.x = f2bf(v.x); o.y = f2bf(v.y); o.z = f2bf(v.z); o.w = f2bf(v.w);
  *(ushort4*)(dst + i * 4) = o;
}

// ============ mega-pack ============
#define PK_N0 2621440L   // Wihh
#define PK_N1 524288L    // Wfz
#define PK_N2 524288L    // Wfz2
#define PK_N3 65536L     // Wgen
#define PK_N4 262144L    // Wh2hb (plain)
#define PK_N5 3072L      // biases
#define PK_N6 3407872L   // embed
__global__ void mega_pack_k(
    const float* __restrict__ W_ih, const float* __restrict__ W_hh,
    const float* __restrict__ Wf1, const float* __restrict__ Wf2,
    const float* __restrict__ Wz, const float* __restrict__ W_gen,
    const float* __restrict__ W_h2h,
    const float* __restrict__ b_ih, const float* __restrict__ b_hh,
    const float* __restrict__ bf2, const float* __restrict__ bz,
    const float* __restrict__ emb_table, const int* __restrict__ text,
    unsigned short* __restrict__ Wihh, unsigned short* __restrict__ Wfz,
    unsigned short* __restrict__ Wfz2, unsigned short* __restrict__ Wgenb,
    unsigned short* __restrict__ Wh2hb, float* __restrict__ biasG,
    float* __restrict__ biasFZ, unsigned short* __restrict__ embb) {
  long q = (long)blockIdx.x * 256 + threadIdx.x;
  if (q < PK_N0) {
    const int row = (int)(q / 1280), c = (int)(q % 1280);
    const float v = (c < 768) ? W_ih[(long)row * 768 + c] : W_hh[(long)row * 512 + (c - 768)];
    Wihh[q] = f2bf(v);
    return;
  }
  q -= PK_N0;
  if (q < PK_N1) {
    const int row = (int)(q >> 9), k = (int)(q & 511);
    const float v = (row < 512) ? Wf1[(long)row * 512 + k] : Wz[(long)(row - 512) * 1024 + k];
    Wfz[q] = f2bf(v);
    return;
  }
  q -= PK_N1;
  if (q < PK_N2) {
    const int row = (int)(q >> 9), k = (int)(q & 511);
    const float v = (row < 512) ? Wf2[(long)row * 512 + k]
                                : Wz[(long)(row - 512) * 1024 + 512 + k];
    Wfz2[q] = f2bf(v);
    return;
  }
  q -= PK_N2;
  if (q < PK_N3) {
    const int row = (int)(q >> 9), k = (int)(q & 511);
    Wgenb[q] = (row < NCLS_) ? f2bf(W_gen[(long)row * 512 + k]) : (unsigned short)0;
    return;
  }
  q -= PK_N3;
  if (q < PK_N4) {
    Wh2hb[q] = f2bf(W_h2h[q]);
    return;
  }
  q -= PK_N4;
  if (q < PK_N5) {
    if (q < 2048) biasG[q] = b_ih[q] + b_hh[q];
    else {
      const int j = (int)(q - 2048);
      biasFZ[j] = (j < 512) ? bf2[j] : bz[j - 512];
    }
    return;
  }
  q -= PK_N5;
  if (q < PK_N6) {
    const long bs = q >> 8;
    const int j = (int)(q & 255);
    const int t = text[bs];
    embb[q] = f2bf(emb_table[(long)t * 256 + j]);
  }
}

extern "C" void kernel_launch(void* const* d_in, const int* in_sizes, int n_in,
                              void* d_out, int out_size, void* d_ws, size_t ws_size,
                              hipStream_t stream) {
  (void)in_sizes; (void)n_in; (void)out_size; (void)ws_size;
  const float* batch_H  = (const float*)d_in[0];
  const float* AS       = (const float*)d_in[1];
  const int*   text     = (const int*)d_in[2];
  const float* W_i2h    = (const float*)d_in[3];
  const float* W_h2h    = (const float*)d_in[4];
  const float* b_h2h    = (const float*)d_in[5];
  const float* w_score  = (const float*)d_in[6];
  const float* W_ih     = (const float*)d_in[7];
  const float* W_hh     = (const float*)d_in[8];
  const float* b_ih     = (const float*)d_in[9];
  const float* b_hh     = (const float*)d_in[10];
  const float* Wf1      = (const float*)d_in[11];
  const float* bf1      = (const float*)d_in[12];
  const float* Wf2      = (const float*)d_in[13];
  const float* bf2      = (const float*)d_in[14];
  const float* Wz       = (const float*)d_in[15];
  const float* bz       = (const float*)d_in[16];
  const float* W_gen    = (const float*)d_in[17];
  const float* b_gen    = (const float*)d_in[18];
  const float* emb_tab  = (const float*)d_in[19];

  float* out = (float*)d_out;
  float* out_probs = out;
  float* out_attn  = out + 1291264;
  float* out_hid   = out + 2143232;
  float* out_char  = out + 8958976;

  char* wsp = (char*)d_ws;
  auto alloc = [&](size_t bytes) { char* p = wsp; wsp += (bytes + 255) & ~(size_t)255; return p; };
  unsigned short* bH    = (unsigned short*)alloc(33554432);
  unsigned short* Hproj = (unsigned short*)alloc(33554432);
  unsigned short* ASb   = (unsigned short*)alloc(13631488);
  unsigned short* embb  = (unsigned short*)alloc(6815744);
  unsigned short* FZpre = (unsigned short*)alloc(27262976);
  unsigned short* Wh2hb = (unsigned short*)alloc(524288);
  unsigned short* Wfz   = (unsigned short*)alloc(1048576);
  unsigned short* Wfz2  = (unsigned short*)alloc(1048576);
  unsigned short* Wihh  = (unsigned short*)alloc(5242880);
  unsigned short* Wgenb = (unsigned short*)alloc(131072);
  unsigned short* Wi2hb = (unsigned short*)alloc(524288);
  float* biasG          = (float*)alloc(8192);
  float* biasFZ         = (float*)alloc(4096);
  unsigned* bars        = (unsigned*)alloc(1024);
  char* ab = (char*)ASb;
  unsigned short* ctx   = (unsigned short*)(ab);
  unsigned short* Ichar = (unsigned short*)(ab + 524288);
  float* cbuf           = (float*)(ab + 1048576);
  unsigned short* hbuf  = (unsigned short*)(ab + 2097152);
  float* hp             = (float*)(ab + 3145728);

  // -------- prologue --------
  mega_cvt_k<<<dim3(23297), dim3(256), 0, stream>>>(batch_H, AS, W_i2h, bH, ASb, Wi2hb);
  mega_pack_k<<<dim3(28960), dim3(256), 0, stream>>>(
      W_ih, W_hh, Wf1, Wf2, Wz, W_gen, W_h2h, b_ih, b_hh, bf2, bz, emb_tab, text,
      Wihh, Wfz, Wfz2, Wgenb, Wh2hb, biasG, biasFZ, embb);

  gemm_tiled_k<false><<<dim3(4, 256), dim3(256), 0, stream>>>(
      bH, Wi2hb, nullptr, nullptr, Hproj, 512, 512, 512);

  gemm_tiled_k<false><<<dim3(8, 104), dim3(256), 0, stream>>>(
      ASb, Wfz2, biasFZ, nullptr, FZpre, 512, 1024, 1024);

  hipMemsetAsync(cbuf, 0, 1048576, stream);
  hipMemsetAsync(hbuf, 0, 1048576, stream);
  hipMemsetAsync(bars, 0, 1024, stream);

  // -------- persistent 26-step scan (256 blocks x 1024 thr) --------
  CoopArgs ca;
  ca.Hproj = Hproj; ca.bH = bH; ca.Wh2hb = Wh2hb; ca.Wfz = Wfz; ca.FZpre = FZpre;
  ca.Wihh = Wihh; ca.embb = embb;
  ca.b_h2h = b_h2h; ca.w_score = w_score; ca.bf1 = bf1; ca.biasG = biasG;
  ca.hp = hp; ca.out_attn = out_attn; ca.out_char = out_char; ca.out_hid = out_hid;
  ca.cbuf = cbuf; ca.ctx = ctx; ca.Ichar = Ichar; ca.hbuf = hbuf; ca.bars = bars;
  void* kargs[] = { (void*)&ca };
  hipLaunchCooperativeKernel((const void*)scan_coop_k, dim3(256), dim3(1024), kargs, 0, stream);

  // probs = out_hid @ W_gen^T + b_gen
  probs_k<<<dim3(2, 208), dim3(256), 0, stream>>>(out_hid, Wgenb, b_gen, out_probs);
}